// Round 1
// baseline (157.166 us; speedup 1.0000x reference)
//
#include <hip/hip_runtime.h>
#include <hip/hip_bf16.h>
#include <math.h>

#define NN 4096
#define DD 1024
#define NCLS 128
#define TAU 0.5f
#define EPSV 1e-8f
#define NB_GEMM 528

typedef __bf16 bf16;
typedef __bf16 bf16x8 __attribute__((ext_vector_type(8)));
typedef __bf16 bf16x4 __attribute__((ext_vector_type(4)));
typedef float f32x4 __attribute__((ext_vector_type(4)));

__device__ __forceinline__ void gl2lds16(const void* g, void* l) {
    __builtin_amdgcn_global_load_lds(
        (const __attribute__((address_space(1))) void*)g,
        (__attribute__((address_space(3))) void*)l,
        16, 0, 0);
}

// K1: block 0 = class stats (cnt, first/second min index) + per-row first-pos
//     index fpos[i]; blocks 1..NN/4 = per-row L2 norm -> normalized bf16 copy,
//     zero rowsum/posv. The two halves are input-independent -> run concurrently
//     in one dispatch instead of two serial ones.
__global__ __launch_bounds__(256) void k_prep(const float* __restrict__ X,
                                              const int* __restrict__ y,
                                              bf16* __restrict__ Xn,
                                              float* __restrict__ rsum,
                                              float* __restrict__ posv,
                                              int* __restrict__ cnt,
                                              int* __restrict__ fpos,
                                              int* __restrict__ ctr) {
    const int t = threadIdx.x;
    if (blockIdx.x == 0) {
        __shared__ int sc[NCLS], s1[NCLS], s2[NCLS];
        if (t < NCLS) { sc[t] = 0; s1[t] = 0x7fffffff; s2[t] = 0x7fffffff; }
        if (t == 0) *ctr = 0;
        __syncthreads();
        int yv[16];
#pragma unroll
        for (int k = 0; k < 16; ++k) {
            int i = t + k * 256;
            yv[k] = y[i];
            atomicAdd(&sc[yv[k]], 1);
            atomicMin(&s1[yv[k]], i);
        }
        __syncthreads();
#pragma unroll
        for (int k = 0; k < 16; ++k) {
            int i = t + k * 256;
            if (s1[yv[k]] != i) atomicMin(&s2[yv[k]], i);
        }
        __syncthreads();
#pragma unroll
        for (int k = 0; k < 16; ++k) {
            int i = t + k * 256;
            int c = yv[k];
            fpos[i] = (sc[c] >= 2) ? (s1[c] == i ? s2[c] : s1[c]) : -1;
        }
        if (t < NCLS) cnt[t] = sc[t];
        return;
    }
    const int w = t >> 6, lane = t & 63;
    const int row = (blockIdx.x - 1) * 4 + w;
    const float* xr = X + (size_t)row * DD;
    float4 v[4];
    float ss = 0.f;
#pragma unroll
    for (int c = 0; c < 4; ++c) {
        v[c] = *(const float4*)(xr + c * 256 + lane * 4);
        ss += v[c].x * v[c].x + v[c].y * v[c].y + v[c].z * v[c].z + v[c].w * v[c].w;
    }
#pragma unroll
    for (int m = 1; m < 64; m <<= 1) ss += __shfl_xor(ss, m, 64);
    float rn = 1.f / fmaxf(sqrtf(ss), EPSV);
    if (lane == 0) { rsum[row] = 0.f; posv[row] = 0.f; }
#pragma unroll
    for (int c = 0; c < 4; ++c) {
        bf16x4 o;
        o.x = (bf16)(v[c].x * rn);
        o.y = (bf16)(v[c].y * rn);
        o.z = (bf16)(v[c].z * rn);
        o.w = (bf16)(v[c].w * rn);
        *(bf16x4*)(Xn + (size_t)row * DD + c * 256 + lane * 4) = o;
    }
}

// K2: upper-triangle 128x128-tile bf16 MFMA gram, fused exp/mask epilogue with
// row+col rowsum reduction, fused posv extraction (S[i, fp(i)] is a gram
// element), and last-block finalize via completion counter (all cross-block
// data flows through device-scope atomics; fences order the counter).
__global__ __launch_bounds__(256) void k_gemm(const bf16* __restrict__ Xn,
                                              const int* __restrict__ y,
                                              const int* __restrict__ fpos,
                                              const int* __restrict__ cnt,
                                              float* __restrict__ rowsum,
                                              float* __restrict__ posv,
                                              int* __restrict__ ctr,
                                              float* __restrict__ out) {
    __shared__ __align__(16) bf16 As[128 * 32];
    __shared__ __align__(16) bf16 Bs[128 * 32];
    __shared__ int yA[128], yB[128], fA[128], fB[128];
    __shared__ int isLast;
    __shared__ float wred[4];

    // decode linear block id -> (bi, bj), bi <= bj
    int id = blockIdx.x;
    float ff = sqrtf((float)(8 * id + 1));
    int bj = (int)((ff - 1.f) * 0.5f);
    if (bj * (bj + 1) / 2 > id) bj--;
    if ((bj + 1) * (bj + 2) / 2 <= id) bj++;
    int bi = id - bj * (bj + 1) / 2;
    const int rowA0 = bi * 128;
    const int rowB0 = bj * 128;
    const bool diag = (bi == bj);

    const int tid = threadIdx.x;
    if (tid < 128) { yA[tid] = y[rowA0 + tid]; fA[tid] = fpos[rowA0 + tid]; }
    else { yB[tid - 128] = y[rowB0 + tid - 128]; fB[tid - 128] = fpos[rowB0 + tid - 128]; }

    const int lane = tid & 63;
    const int w = tid >> 6;
    const int wm = w & 1, wn = w >> 1;     // 2x2 waves -> each wave 64x64
    const int lr = lane >> 4, lc = lane & 15;

    f32x4 acc[4][4];
#pragma unroll
    for (int i = 0; i < 4; ++i)
#pragma unroll
        for (int j = 0; j < 4; ++j) acc[i][j] = (f32x4){0.f, 0.f, 0.f, 0.f};

    // staging with k-slot XOR swizzle: slot g of row r holds k-group g^((r>>1)&3)
    const int r = tid >> 2;
    const int g = tid & 3;
    const int kg = g ^ ((r >> 1) & 3);
    const bf16* gA0 = Xn + (size_t)(rowA0 + r) * DD + kg * 8;
    const bf16* gA1 = gA0 + (size_t)64 * DD;
    const bf16* gB0 = Xn + (size_t)(rowB0 + r) * DD + kg * 8;
    const bf16* gB1 = gB0 + (size_t)64 * DD;
    bf16* lA0 = As + tid * 8;
    bf16* lA1 = As + 64 * 32 + tid * 8;
    bf16* lB0 = Bs + tid * 8;
    bf16* lB1 = Bs + 64 * 32 + tid * 8;

    const int sw = (lc >> 1) & 3;   // read-side swizzle (row = ...16*mt + lc)

    for (int k0 = 0; k0 < DD; k0 += 32) {
        __syncthreads();
        gl2lds16(gA0 + k0, lA0);
        gl2lds16(gA1 + k0, lA1);
        gl2lds16(gB0 + k0, lB0);
        gl2lds16(gB1 + k0, lB1);
        __syncthreads();

        bf16x8 af[4], bfr[4];
#pragma unroll
        for (int mt = 0; mt < 4; ++mt)
            af[mt] = *(const bf16x8*)(As + (wm * 64 + mt * 16 + lc) * 32 + ((lr ^ sw) * 8));
#pragma unroll
        for (int nt = 0; nt < 4; ++nt)
            bfr[nt] = *(const bf16x8*)(Bs + (wn * 64 + nt * 16 + lc) * 32 + ((lr ^ sw) * 8));
#pragma unroll
        for (int mt = 0; mt < 4; ++mt)
#pragma unroll
            for (int nt = 0; nt < 4; ++nt)
                acc[mt][nt] = __builtin_amdgcn_mfma_f32_16x16x32_bf16(
                    af[mt], bfr[nt], acc[mt][nt], 0, 0, 0);
    }

    // Epilogue: S=(c+1)*0.25; mask same-class (incl. diagonal); row+col exp-sums;
    // posv extraction where (row,col) hits a (i, fp(i)) pair.
    int cloc[4], ycol[4], fcol[4];
    bool pcol[4];
#pragma unroll
    for (int nt = 0; nt < 4; ++nt) {
        cloc[nt] = wn * 64 + nt * 16 + lc;
        ycol[nt] = yB[cloc[nt]];
        fcol[nt] = fB[cloc[nt]];
        pcol[nt] = ((unsigned)(fcol[nt] - rowA0) < 128u);
    }
    float colacc[4] = {0.f, 0.f, 0.f, 0.f};
#pragma unroll
    for (int mt = 0; mt < 4; ++mt) {
#pragma unroll
        for (int rr = 0; rr < 4; ++rr) {
            int rloc = wm * 64 + mt * 16 + lr * 4 + rr;  // C row = (lane>>4)*4+reg
            int rglob = rowA0 + rloc;
            int yrow = yA[rloc];
            int fprow = fA[rloc];
            bool prow = ((unsigned)(fprow - rowB0) < 128u);
            float s = 0.f;
#pragma unroll
            for (int nt = 0; nt < 4; ++nt) {
                float Sv = (acc[mt][nt][rr] + 1.f) * (0.5f * TAU);
                int cg = rowB0 + cloc[nt];
                if (prow && cg == fprow) atomicExch(&posv[rglob], Sv);
                if (pcol[nt] && fcol[nt] == rglob) atomicExch(&posv[cg], Sv);
                float e = (ycol[nt] != yrow) ? __expf(Sv) : 0.f;
                s += e;
                colacc[nt] += e;
            }
            s += __shfl_xor(s, 1, 16);
            s += __shfl_xor(s, 2, 16);
            s += __shfl_xor(s, 4, 16);
            s += __shfl_xor(s, 8, 16);
            if (lc == 0) atomicAdd(&rowsum[rglob], s);
        }
    }
    if (!diag) {
#pragma unroll
        for (int nt = 0; nt < 4; ++nt) {
            float cs = colacc[nt];
            cs += __shfl_xor(cs, 16, 64);
            cs += __shfl_xor(cs, 32, 64);
            if (lane < 16) atomicAdd(&rowsum[rowB0 + wn * 64 + nt * 16 + lane], cs);
        }
    }

    // ---- completion counter + last-block finalize ----
    __threadfence();               // drain this block's atomics to device scope
    __syncthreads();
    if (tid == 0) isLast = (atomicAdd(ctr, 1) == NB_GEMM - 1);
    __syncthreads();
    if (!isLast) return;
    __threadfence();               // acquire

    float acc2 = 0.f;
#pragma unroll
    for (int k = 0; k < 16; ++k) {
        int i = tid + k * 256;
        float rs = atomicAdd(&rowsum[i], 0.0f);   // device-coherent read
        float pv = atomicAdd(&posv[i], 0.0f);     // device-coherent read
        float tot = rs + __expf(pv) + (float)(NN - 2 + cnt[y[i]]);
        acc2 += logf(tot) - pv;
    }
#pragma unroll
    for (int m = 1; m < 64; m <<= 1) acc2 += __shfl_xor(acc2, m, 64);
    if ((tid & 63) == 0) wred[tid >> 6] = acc2;
    __syncthreads();
    if (tid == 0) *out = (wred[0] + wred[1] + wred[2] + wred[3]) / (float)NN;
}

extern "C" void kernel_launch(void* const* d_in, const int* in_sizes, int n_in,
                              void* d_out, int out_size, void* d_ws, size_t ws_size,
                              hipStream_t stream) {
    const float* X = (const float*)d_in[0];
    const int* y = (const int*)d_in[1];
    float* out = (float*)d_out;

    char* ws = (char*)d_ws;
    bf16* Xn    = (bf16*)ws;                                   // 8 MB
    float* rsum = (float*)(ws + 8 * 1024 * 1024);              // 16 KB
    float* posv = (float*)(ws + 8 * 1024 * 1024 + 16 * 1024);  // 16 KB
    int* cnt    = (int*)(ws + 8 * 1024 * 1024 + 32 * 1024);    // 512 B
    int* ctr    = (int*)(ws + 8 * 1024 * 1024 + 32 * 1024 + 512);
    int* fpos   = (int*)(ws + 8 * 1024 * 1024 + 36 * 1024);    // 16 KB

    k_prep<<<dim3(NN / 4 + 1), 256, 0, stream>>>(X, y, Xn, rsum, posv, cnt, fpos, ctr);
    k_gemm<<<dim3(NB_GEMM), 256, 0, stream>>>(Xn, y, fpos, cnt, rsum, posv, ctr, out);
}

// Round 2
// 104.661 us; speedup vs baseline: 1.5017x; 1.5017x over previous
//
#include <hip/hip_runtime.h>
#include <hip/hip_bf16.h>
#include <math.h>

#define NN 4096
#define DD 1024
#define NCLS 128
#define TAU 0.5f
#define EPSV 1e-8f
#define NB_GEMM 528

typedef __bf16 bf16;
typedef __bf16 bf16x8 __attribute__((ext_vector_type(8)));
typedef __bf16 bf16x4 __attribute__((ext_vector_type(4)));
typedef float f32x4 __attribute__((ext_vector_type(4)));

__device__ __forceinline__ void gl2lds16(const void* g, void* l) {
    __builtin_amdgcn_global_load_lds(
        (const __attribute__((address_space(1))) void*)g,
        (__attribute__((address_space(3))) void*)l,
        16, 0, 0);
}

// K1: block 0 = class stats (cnt, first/second min index) -> per-row first-pos
//     index fpos[i]; blocks 1..NN/4 = per-row L2 norm -> normalized bf16 copy,
//     zero rowsum/posv. Input-independent halves run concurrently in one dispatch.
__global__ __launch_bounds__(256) void k_prep(const float* __restrict__ X,
                                              const int* __restrict__ y,
                                              bf16* __restrict__ Xn,
                                              float* __restrict__ rsum,
                                              float* __restrict__ posv,
                                              int* __restrict__ cnt,
                                              int* __restrict__ fpos) {
    const int t = threadIdx.x;
    if (blockIdx.x == 0) {
        __shared__ int sc[NCLS], s1[NCLS], s2[NCLS];
        if (t < NCLS) { sc[t] = 0; s1[t] = 0x7fffffff; s2[t] = 0x7fffffff; }
        __syncthreads();
        int yv[16];
#pragma unroll
        for (int k = 0; k < 16; ++k) {
            int i = t + k * 256;
            yv[k] = y[i];
            atomicAdd(&sc[yv[k]], 1);
            atomicMin(&s1[yv[k]], i);
        }
        __syncthreads();
#pragma unroll
        for (int k = 0; k < 16; ++k) {
            int i = t + k * 256;
            if (s1[yv[k]] != i) atomicMin(&s2[yv[k]], i);
        }
        __syncthreads();
#pragma unroll
        for (int k = 0; k < 16; ++k) {
            int i = t + k * 256;
            int c = yv[k];
            fpos[i] = (sc[c] >= 2) ? (s1[c] == i ? s2[c] : s1[c]) : -1;
        }
        if (t < NCLS) cnt[t] = sc[t];
        return;
    }
    const int w = t >> 6, lane = t & 63;
    const int row = (blockIdx.x - 1) * 4 + w;
    const float* xr = X + (size_t)row * DD;
    float4 v[4];
    float ss = 0.f;
#pragma unroll
    for (int c = 0; c < 4; ++c) {
        v[c] = *(const float4*)(xr + c * 256 + lane * 4);
        ss += v[c].x * v[c].x + v[c].y * v[c].y + v[c].z * v[c].z + v[c].w * v[c].w;
    }
#pragma unroll
    for (int m = 1; m < 64; m <<= 1) ss += __shfl_xor(ss, m, 64);
    float rn = 1.f / fmaxf(sqrtf(ss), EPSV);
    if (lane == 0) { rsum[row] = 0.f; posv[row] = 0.f; }
#pragma unroll
    for (int c = 0; c < 4; ++c) {
        bf16x4 o;
        o.x = (bf16)(v[c].x * rn);
        o.y = (bf16)(v[c].y * rn);
        o.z = (bf16)(v[c].z * rn);
        o.w = (bf16)(v[c].w * rn);
        *(bf16x4*)(Xn + (size_t)row * DD + c * 256 + lane * 4) = o;
    }
}

// K2: upper-triangle 128x128-tile bf16 MFMA gram with fused exp/mask epilogue,
// row+col rowsum reduction (symmetry), and posv extraction (S[i,fp(i)] is a
// gram element; plain store — visibility to k_finalize via kernel boundary).
// NO device-scope fences here: they trigger per-XCD L2 writeback/invalidate
// that destroys Xn L2-reuse for still-running blocks (round-1 lesson: 93us).
__global__ __launch_bounds__(256) void k_gemm(const bf16* __restrict__ Xn,
                                              const int* __restrict__ y,
                                              const int* __restrict__ fpos,
                                              float* __restrict__ rowsum,
                                              float* __restrict__ posv) {
    __shared__ __align__(16) bf16 As[128 * 32];
    __shared__ __align__(16) bf16 Bs[128 * 32];
    __shared__ int yA[128], yB[128], fA[128], fB[128];

    // decode linear block id -> (bi, bj), bi <= bj
    int id = blockIdx.x;
    float ff = sqrtf((float)(8 * id + 1));
    int bj = (int)((ff - 1.f) * 0.5f);
    if (bj * (bj + 1) / 2 > id) bj--;
    if ((bj + 1) * (bj + 2) / 2 <= id) bj++;
    int bi = id - bj * (bj + 1) / 2;
    const int rowA0 = bi * 128;
    const int rowB0 = bj * 128;
    const bool diag = (bi == bj);

    const int tid = threadIdx.x;
    if (tid < 128) { yA[tid] = y[rowA0 + tid]; fA[tid] = fpos[rowA0 + tid]; }
    else { yB[tid - 128] = y[rowB0 + tid - 128]; fB[tid - 128] = fpos[rowB0 + tid - 128]; }

    const int lane = tid & 63;
    const int w = tid >> 6;
    const int wm = w & 1, wn = w >> 1;     // 2x2 waves -> each wave 64x64
    const int lr = lane >> 4, lc = lane & 15;

    f32x4 acc[4][4];
#pragma unroll
    for (int i = 0; i < 4; ++i)
#pragma unroll
        for (int j = 0; j < 4; ++j) acc[i][j] = (f32x4){0.f, 0.f, 0.f, 0.f};

    // staging with k-slot XOR swizzle: slot g of row r holds k-group g^((r>>1)&3)
    const int r = tid >> 2;
    const int g = tid & 3;
    const int kg = g ^ ((r >> 1) & 3);
    const bf16* gA0 = Xn + (size_t)(rowA0 + r) * DD + kg * 8;
    const bf16* gA1 = gA0 + (size_t)64 * DD;
    const bf16* gB0 = Xn + (size_t)(rowB0 + r) * DD + kg * 8;
    const bf16* gB1 = gB0 + (size_t)64 * DD;
    bf16* lA0 = As + tid * 8;
    bf16* lA1 = As + 64 * 32 + tid * 8;
    bf16* lB0 = Bs + tid * 8;
    bf16* lB1 = Bs + 64 * 32 + tid * 8;

    const int sw = (lc >> 1) & 3;   // read-side swizzle (row = ...16*mt + lc)

    for (int k0 = 0; k0 < DD; k0 += 32) {
        __syncthreads();
        gl2lds16(gA0 + k0, lA0);
        gl2lds16(gA1 + k0, lA1);
        gl2lds16(gB0 + k0, lB0);
        gl2lds16(gB1 + k0, lB1);
        __syncthreads();

        bf16x8 af[4], bfr[4];
#pragma unroll
        for (int mt = 0; mt < 4; ++mt)
            af[mt] = *(const bf16x8*)(As + (wm * 64 + mt * 16 + lc) * 32 + ((lr ^ sw) * 8));
#pragma unroll
        for (int nt = 0; nt < 4; ++nt)
            bfr[nt] = *(const bf16x8*)(Bs + (wn * 64 + nt * 16 + lc) * 32 + ((lr ^ sw) * 8));
#pragma unroll
        for (int mt = 0; mt < 4; ++mt)
#pragma unroll
            for (int nt = 0; nt < 4; ++nt)
                acc[mt][nt] = __builtin_amdgcn_mfma_f32_16x16x32_bf16(
                    af[mt], bfr[nt], acc[mt][nt], 0, 0, 0);
    }

    // Epilogue: S=(c+1)*0.25; mask same-class (incl. diagonal); row+col exp-sums;
    // posv where (row,col) hits an (i, fp(i)) pair.
    int cloc[4], ycol[4], fcol[4];
    bool pcol[4];
#pragma unroll
    for (int nt = 0; nt < 4; ++nt) {
        cloc[nt] = wn * 64 + nt * 16 + lc;
        ycol[nt] = yB[cloc[nt]];
        fcol[nt] = fB[cloc[nt]];
        pcol[nt] = ((unsigned)(fcol[nt] - rowA0) < 128u);
    }
    float colacc[4] = {0.f, 0.f, 0.f, 0.f};
#pragma unroll
    for (int mt = 0; mt < 4; ++mt) {
#pragma unroll
        for (int rr = 0; rr < 4; ++rr) {
            int rloc = wm * 64 + mt * 16 + lr * 4 + rr;  // C row = (lane>>4)*4+reg
            int rglob = rowA0 + rloc;
            int yrow = yA[rloc];
            int fprow = fA[rloc];
            bool prow = ((unsigned)(fprow - rowB0) < 128u);
            float s = 0.f;
#pragma unroll
            for (int nt = 0; nt < 4; ++nt) {
                float Sv = (acc[mt][nt][rr] + 1.f) * (0.5f * TAU);
                int cg = rowB0 + cloc[nt];
                if (prow && cg == fprow) posv[rglob] = Sv;
                if (pcol[nt] && fcol[nt] == rglob) posv[cg] = Sv;
                float e = (ycol[nt] != yrow) ? __expf(Sv) : 0.f;
                s += e;
                colacc[nt] += e;
            }
            s += __shfl_xor(s, 1, 16);
            s += __shfl_xor(s, 2, 16);
            s += __shfl_xor(s, 4, 16);
            s += __shfl_xor(s, 8, 16);
            if (lc == 0) atomicAdd(&rowsum[rglob], s);
        }
    }
    if (!diag) {
#pragma unroll
        for (int nt = 0; nt < 4; ++nt) {
            float cs = colacc[nt];
            cs += __shfl_xor(cs, 16, 64);
            cs += __shfl_xor(cs, 32, 64);
            if (lane < 16) atomicAdd(&rowsum[rowB0 + wn * 64 + nt * 16 + lane], cs);
        }
    }
}

// K3: single block; lse_i = log(rowsum_i + exp(pv_i) + (N-2+cnt)); out = mean(lse - pv)
__global__ __launch_bounds__(1024) void k_finalize(const float* __restrict__ rowsum,
                                                   const float* __restrict__ posv,
                                                   const int* __restrict__ y,
                                                   const int* __restrict__ cnt,
                                                   float* __restrict__ out) {
    int t = threadIdx.x;
    float acc = 0.f;
#pragma unroll
    for (int k = 0; k < 4; ++k) {
        int i = t + k * 1024;
        float pv = posv[i];
        float tot = rowsum[i] + __expf(pv) + (float)(NN - 2 + cnt[y[i]]);
        acc += logf(tot) - pv;
    }
#pragma unroll
    for (int m = 1; m < 64; m <<= 1) acc += __shfl_xor(acc, m, 64);
    __shared__ float wsum[16];
    int w = t >> 6, lane = t & 63;
    if (lane == 0) wsum[w] = acc;
    __syncthreads();
    if (t == 0) {
        float s = 0.f;
#pragma unroll
        for (int q = 0; q < 16; ++q) s += wsum[q];
        *out = s / (float)NN;
    }
}

extern "C" void kernel_launch(void* const* d_in, const int* in_sizes, int n_in,
                              void* d_out, int out_size, void* d_ws, size_t ws_size,
                              hipStream_t stream) {
    const float* X = (const float*)d_in[0];
    const int* y = (const int*)d_in[1];
    float* out = (float*)d_out;

    char* ws = (char*)d_ws;
    bf16* Xn    = (bf16*)ws;                                   // 8 MB
    float* rsum = (float*)(ws + 8 * 1024 * 1024);              // 16 KB
    float* posv = (float*)(ws + 8 * 1024 * 1024 + 16 * 1024);  // 16 KB
    int* cnt    = (int*)(ws + 8 * 1024 * 1024 + 32 * 1024);    // 512 B
    int* fpos   = (int*)(ws + 8 * 1024 * 1024 + 36 * 1024);    // 16 KB

    k_prep<<<dim3(NN / 4 + 1), 256, 0, stream>>>(X, y, Xn, rsum, posv, cnt, fpos);
    k_gemm<<<dim3(NB_GEMM), 256, 0, stream>>>(Xn, y, fpos, rsum, posv);
    k_finalize<<<dim3(1), 1024, 0, stream>>>(rsum, posv, y, cnt, out);
}

// Round 3
// 103.995 us; speedup vs baseline: 1.5113x; 1.0064x over previous
//
#include <hip/hip_runtime.h>
#include <hip/hip_bf16.h>
#include <math.h>

#define NN 4096
#define DD 1024
#define NCLS 128
#define TAU 0.5f
#define EPSV 1e-8f
#define NB_GEMM 528   // 32*33/2 upper-triangle tiles; 528 = 8 XCDs * 66

typedef __bf16 bf16;
typedef __bf16 bf16x8 __attribute__((ext_vector_type(8)));
typedef __bf16 bf16x4 __attribute__((ext_vector_type(4)));
typedef float f32x4 __attribute__((ext_vector_type(4)));

__device__ __forceinline__ void gl2lds16(const void* g, void* l) {
    __builtin_amdgcn_global_load_lds(
        (const __attribute__((address_space(1))) void*)g,
        (__attribute__((address_space(3))) void*)l,
        16, 0, 0);
}

// K1: block 0 = class stats (cnt, first/second min index) -> per-row first-pos
//     index fpos[i]; blocks 1..NN/4 = per-row L2 norm -> normalized bf16 copy,
//     zero rowsum/posv. Input-independent halves run concurrently in one dispatch.
__global__ __launch_bounds__(256) void k_prep(const float* __restrict__ X,
                                              const int* __restrict__ y,
                                              bf16* __restrict__ Xn,
                                              float* __restrict__ rsum,
                                              float* __restrict__ posv,
                                              int* __restrict__ cnt,
                                              int* __restrict__ fpos) {
    const int t = threadIdx.x;
    if (blockIdx.x == 0) {
        __shared__ int sc[NCLS], s1[NCLS], s2[NCLS];
        if (t < NCLS) { sc[t] = 0; s1[t] = 0x7fffffff; s2[t] = 0x7fffffff; }
        __syncthreads();
        int yv[16];
#pragma unroll
        for (int k = 0; k < 16; ++k) {
            int i = t + k * 256;
            yv[k] = y[i];
            atomicAdd(&sc[yv[k]], 1);
            atomicMin(&s1[yv[k]], i);
        }
        __syncthreads();
#pragma unroll
        for (int k = 0; k < 16; ++k) {
            int i = t + k * 256;
            if (s1[yv[k]] != i) atomicMin(&s2[yv[k]], i);
        }
        __syncthreads();
#pragma unroll
        for (int k = 0; k < 16; ++k) {
            int i = t + k * 256;
            int c = yv[k];
            fpos[i] = (sc[c] >= 2) ? (s1[c] == i ? s2[c] : s1[c]) : -1;
        }
        if (t < NCLS) cnt[t] = sc[t];
        return;
    }
    const int w = t >> 6, lane = t & 63;
    const int row = (blockIdx.x - 1) * 4 + w;
    const float* xr = X + (size_t)row * DD;
    float4 v[4];
    float ss = 0.f;
#pragma unroll
    for (int c = 0; c < 4; ++c) {
        v[c] = *(const float4*)(xr + c * 256 + lane * 4);
        ss += v[c].x * v[c].x + v[c].y * v[c].y + v[c].z * v[c].z + v[c].w * v[c].w;
    }
#pragma unroll
    for (int m = 1; m < 64; m <<= 1) ss += __shfl_xor(ss, m, 64);
    float rn = 1.f / fmaxf(sqrtf(ss), EPSV);
    if (lane == 0) { rsum[row] = 0.f; posv[row] = 0.f; }
#pragma unroll
    for (int c = 0; c < 4; ++c) {
        bf16x4 o;
        o.x = (bf16)(v[c].x * rn);
        o.y = (bf16)(v[c].y * rn);
        o.z = (bf16)(v[c].z * rn);
        o.w = (bf16)(v[c].w * rn);
        *(bf16x4*)(Xn + (size_t)row * DD + c * 256 + lane * 4) = o;
    }
}

// K2: upper-triangle 128x128-tile bf16 MFMA gram with fused exp/mask epilogue,
// row+col rowsum reduction (symmetry), posv extraction (S[i,fp(i)] is a gram
// element; plain store — visibility to k_finalize via kernel boundary).
// NO device-scope fences (round-1 lesson: per-block L2 wb/inv -> 93us).
// XCD-chunked swizzle (T1): hardware id b lands on XCD b%8; give each XCD 66
// CONSECUTIVE triangle ids (bj-major -> shared B-panels + lockstep A k-slices
// stay L2-resident instead of thrashing to L3).
__global__ __launch_bounds__(256) void k_gemm(const bf16* __restrict__ Xn,
                                              const int* __restrict__ y,
                                              const int* __restrict__ fpos,
                                              float* __restrict__ rowsum,
                                              float* __restrict__ posv) {
    __shared__ __align__(16) bf16 As[128 * 32];
    __shared__ __align__(16) bf16 Bs[128 * 32];
    __shared__ int yA[128], yB[128], fA[128], fB[128];

    // bijective XCD swizzle: 528 = 8 * 66
    int id = (blockIdx.x & 7) * 66 + (blockIdx.x >> 3);
    // decode linear id -> (bi, bj), bi <= bj
    float ff = sqrtf((float)(8 * id + 1));
    int bj = (int)((ff - 1.f) * 0.5f);
    if (bj * (bj + 1) / 2 > id) bj--;
    if ((bj + 1) * (bj + 2) / 2 <= id) bj++;
    int bi = id - bj * (bj + 1) / 2;
    const int rowA0 = bi * 128;
    const int rowB0 = bj * 128;
    const bool diag = (bi == bj);

    const int tid = threadIdx.x;
    if (tid < 128) { yA[tid] = y[rowA0 + tid]; fA[tid] = fpos[rowA0 + tid]; }
    else { yB[tid - 128] = y[rowB0 + tid - 128]; fB[tid - 128] = fpos[rowB0 + tid - 128]; }

    const int lane = tid & 63;
    const int w = tid >> 6;
    const int wm = w & 1, wn = w >> 1;     // 2x2 waves -> each wave 64x64
    const int lr = lane >> 4, lc = lane & 15;

    f32x4 acc[4][4];
#pragma unroll
    for (int i = 0; i < 4; ++i)
#pragma unroll
        for (int j = 0; j < 4; ++j) acc[i][j] = (f32x4){0.f, 0.f, 0.f, 0.f};

    // staging with k-slot XOR swizzle: slot g of row r holds k-group g^((r>>1)&3)
    const int r = tid >> 2;
    const int g = tid & 3;
    const int kg = g ^ ((r >> 1) & 3);
    const bf16* gA0 = Xn + (size_t)(rowA0 + r) * DD + kg * 8;
    const bf16* gA1 = gA0 + (size_t)64 * DD;
    const bf16* gB0 = Xn + (size_t)(rowB0 + r) * DD + kg * 8;
    const bf16* gB1 = gB0 + (size_t)64 * DD;
    bf16* lA0 = As + tid * 8;
    bf16* lA1 = As + 64 * 32 + tid * 8;
    bf16* lB0 = Bs + tid * 8;
    bf16* lB1 = Bs + 64 * 32 + tid * 8;

    const int sw = (lc >> 1) & 3;   // read-side swizzle (row = ...16*mt + lc)

    for (int k0 = 0; k0 < DD; k0 += 32) {
        __syncthreads();
        gl2lds16(gA0 + k0, lA0);
        gl2lds16(gA1 + k0, lA1);
        gl2lds16(gB0 + k0, lB0);
        gl2lds16(gB1 + k0, lB1);
        __syncthreads();

        bf16x8 af[4], bfr[4];
#pragma unroll
        for (int mt = 0; mt < 4; ++mt)
            af[mt] = *(const bf16x8*)(As + (wm * 64 + mt * 16 + lc) * 32 + ((lr ^ sw) * 8));
#pragma unroll
        for (int nt = 0; nt < 4; ++nt)
            bfr[nt] = *(const bf16x8*)(Bs + (wn * 64 + nt * 16 + lc) * 32 + ((lr ^ sw) * 8));
#pragma unroll
        for (int mt = 0; mt < 4; ++mt)
#pragma unroll
            for (int nt = 0; nt < 4; ++nt)
                acc[mt][nt] = __builtin_amdgcn_mfma_f32_16x16x32_bf16(
                    af[mt], bfr[nt], acc[mt][nt], 0, 0, 0);
    }

    // Epilogue: S=(c+1)*0.25; mask same-class (incl. diagonal); row+col exp-sums;
    // posv where (row,col) hits an (i, fp(i)) pair.
    int cloc[4], ycol[4], fcol[4];
    bool pcol[4];
#pragma unroll
    for (int nt = 0; nt < 4; ++nt) {
        cloc[nt] = wn * 64 + nt * 16 + lc;
        ycol[nt] = yB[cloc[nt]];
        fcol[nt] = fB[cloc[nt]];
        pcol[nt] = ((unsigned)(fcol[nt] - rowA0) < 128u);
    }
    float colacc[4] = {0.f, 0.f, 0.f, 0.f};
#pragma unroll
    for (int mt = 0; mt < 4; ++mt) {
#pragma unroll
        for (int rr = 0; rr < 4; ++rr) {
            int rloc = wm * 64 + mt * 16 + lr * 4 + rr;  // C row = (lane>>4)*4+reg
            int rglob = rowA0 + rloc;
            int yrow = yA[rloc];
            int fprow = fA[rloc];
            bool prow = ((unsigned)(fprow - rowB0) < 128u);
            float s = 0.f;
#pragma unroll
            for (int nt = 0; nt < 4; ++nt) {
                float Sv = (acc[mt][nt][rr] + 1.f) * (0.5f * TAU);
                int cg = rowB0 + cloc[nt];
                if (prow && cg == fprow) posv[rglob] = Sv;
                if (pcol[nt] && fcol[nt] == rglob) posv[cg] = Sv;
                float e = (ycol[nt] != yrow) ? __expf(Sv) : 0.f;
                s += e;
                colacc[nt] += e;
            }
            s += __shfl_xor(s, 1, 16);
            s += __shfl_xor(s, 2, 16);
            s += __shfl_xor(s, 4, 16);
            s += __shfl_xor(s, 8, 16);
            if (lc == 0) atomicAdd(&rowsum[rglob], s);
        }
    }
    if (!diag) {
#pragma unroll
        for (int nt = 0; nt < 4; ++nt) {
            float cs = colacc[nt];
            cs += __shfl_xor(cs, 16, 64);
            cs += __shfl_xor(cs, 32, 64);
            if (lane < 16) atomicAdd(&rowsum[rowB0 + wn * 64 + nt * 16 + lane], cs);
        }
    }
}

// K3: single block; lse_i = log(rowsum_i + exp(pv_i) + (N-2+cnt)); out = mean(lse - pv)
__global__ __launch_bounds__(1024) void k_finalize(const float* __restrict__ rowsum,
                                                   const float* __restrict__ posv,
                                                   const int* __restrict__ y,
                                                   const int* __restrict__ cnt,
                                                   float* __restrict__ out) {
    int t = threadIdx.x;
    float acc = 0.f;
#pragma unroll
    for (int k = 0; k < 4; ++k) {
        int i = t + k * 1024;
        float pv = posv[i];
        float tot = rowsum[i] + __expf(pv) + (float)(NN - 2 + cnt[y[i]]);
        acc += logf(tot) - pv;
    }
#pragma unroll
    for (int m = 1; m < 64; m <<= 1) acc += __shfl_xor(acc, m, 64);
    __shared__ float wsum[16];
    int w = t >> 6, lane = t & 63;
    if (lane == 0) wsum[w] = acc;
    __syncthreads();
    if (t == 0) {
        float s = 0.f;
#pragma unroll
        for (int q = 0; q < 16; ++q) s += wsum[q];
        *out = s / (float)NN;
    }
}

extern "C" void kernel_launch(void* const* d_in, const int* in_sizes, int n_in,
                              void* d_out, int out_size, void* d_ws, size_t ws_size,
                              hipStream_t stream) {
    const float* X = (const float*)d_in[0];
    const int* y = (const int*)d_in[1];
    float* out = (float*)d_out;

    char* ws = (char*)d_ws;
    bf16* Xn    = (bf16*)ws;                                   // 8 MB
    float* rsum = (float*)(ws + 8 * 1024 * 1024);              // 16 KB
    float* posv = (float*)(ws + 8 * 1024 * 1024 + 16 * 1024);  // 16 KB
    int* cnt    = (int*)(ws + 8 * 1024 * 1024 + 32 * 1024);    // 512 B
    int* fpos   = (int*)(ws + 8 * 1024 * 1024 + 36 * 1024);    // 16 KB

    k_prep<<<dim3(NN / 4 + 1), 256, 0, stream>>>(X, y, Xn, rsum, posv, cnt, fpos);
    k_gemm<<<dim3(NB_GEMM), 256, 0, stream>>>(Xn, y, fpos, rsum, posv);
    k_finalize<<<dim3(1), 1024, 0, stream>>>(rsum, posv, y, cnt, out);
}